// Round 3
// baseline (848.615 us; speedup 1.0000x reference)
//
#include <hip/hip_runtime.h>

#define N_FUNC 10000
#define N_IN   2000
#define N_OUT  2000
#define CCH    8
#define K_FF   16
#define E_FF    160000   // ff edges: dst[e] = e/16 (structural), src random func
#define E_W1    168000   // ff+if edges (dst < N_FUNC)
#define E_IF    8000
#define BATCH   64
#define EPS_LN  1e-5f
#define IF_CAP  16        // max if-in-degree of a func node (mean 0.8)
#define HROW    (BATCH * CCH)   // Hsum row: 512 ushorts (bf16) = 1 KB per node
#define NBLK    1024      // 4 blocks/CU x 256 CUs -> all co-resident (launch_bounds 256,4)
#define NWAVE   (NBLK * 4)

typedef float f2 __attribute__((ext_vector_type(2)));   // -> v_pk_fma_f32

// ---- bf16 helpers (fp32 math everywhere; RNE on store) ----
__device__ __forceinline__ f2 bfpair(unsigned int u) {   // packed pair -> 2 floats
    f2 r;
    r.x = __builtin_bit_cast(float, u << 16);
    r.y = __builtin_bit_cast(float, u & 0xffff0000u);
    return r;
}
__device__ __forceinline__ unsigned int bfpack2(float f0, float f1) {
    unsigned int x0 = __builtin_bit_cast(unsigned int, f0);
    unsigned int x1 = __builtin_bit_cast(unsigned int, f1);
    unsigned int r0 = (x0 + 0x7fffu + ((x0 >> 16) & 1u)) >> 16;
    unsigned int r1 = (x1 + 0x7fffu + ((x1 >> 16) & 1u)) & 0xffff0000u;
    return r0 | r1;
}

// fast GELU (validated: absmax unchanged vs exact erf)
__device__ __forceinline__ float fast_gelu(float x) {
    float x2 = x * x;
    float u  = x * __builtin_fmaf(0.044715f, x2, 1.0f);
    float e  = exp2f(-2.3022080f * u);     // sigmoid(1.5957691*u)
    return x * (1.0f / (1.0f + e));
}

// ---- device-scope grid barrier (all NBLK blocks co-resident by construction) ----
__device__ __forceinline__ void gsync(unsigned* bar, unsigned target) {
    __syncthreads();
    if (threadIdx.x == 0) {
        __threadfence();                        // release: publish our stores
        atomicAdd(bar, 1u);                     // device-scope by default on CDNA
        while (__hip_atomic_load(bar, __ATOMIC_RELAXED, __HIP_MEMORY_SCOPE_AGENT) < target)
            __builtin_amdgcn_s_sleep(1);
    }
    __syncthreads();
    __threadfence();                            // acquire: invalidate stale L1/L2 lines
}

// ---------------- shared pieces (float2-packed), round-0 dataflow ----------------

__device__ __forceinline__ void if_accum(
        f2* __restrict__ acc2, const float* __restrict__ xT,
        const float* __restrict__ w1, const float* __restrict__ b3,
        const int* __restrict__ if_cnt, const int* __restrict__ if_bkt,
        int f, int lane, float lf) {
    int icnt = if_cnt[f];
    for (int j = 0; j < icnt; j++) {
        int e = if_bkt[f * IF_CAP + j];
        int ii = (e - E_FF) >> 2;
        float xv = xT[ii * BATCH + lane] + lf * b3[e];
        f2 xv2; xv2.x = xv; xv2.y = xv;
        const f2* w1v = (const f2*)(w1 + (size_t)e * CCH);
        #pragma unroll
        for (int q = 0; q < 4; q++) acc2[q] += xv2 * w1v[q];
    }
}

__device__ __forceinline__ void ln_gelu(
        const f2* __restrict__ acc2, const float* __restrict__ gamma,
        const float* __restrict__ beta, int f, f2* __restrict__ h2) {
    float mu = 0.f;
    #pragma unroll
    for (int q = 0; q < 4; q++) mu += acc2[q].x + acc2[q].y;
    mu *= 0.125f;
    float var = 0.f;
    #pragma unroll
    for (int q = 0; q < 4; q++) {
        float dx = acc2[q].x - mu, dy = acc2[q].y - mu;
        var += dx * dx + dy * dy;
    }
    var *= 0.125f;
    float rs = rsqrtf(var + EPS_LN);
    const f2* gv = (const f2*)(gamma + (size_t)f * CCH);
    const f2* bv = (const f2*)(beta + (size_t)f * CCH);
    f2 mu2; mu2.x = mu; mu2.y = mu;
    f2 rs2; rs2.x = rs; rs2.y = rs;
    #pragma unroll
    for (int q = 0; q < 4; q++) {
        f2 g = (acc2[q] - mu2) * rs2 * gv[q] + bv[q];
        h2[q].x = fast_gelu(g.x);
        h2[q].y = fast_gelu(g.y);
    }
}

// gather-form h for node f, coefficient lf = (layer_idx-1):
// ff in-edge value = lf*b3[e] + dot8(w3[e], Hsum_old[src[e]])
__device__ __forceinline__ void compute_h_gather(
        const unsigned short* __restrict__ Hold, const float* __restrict__ xT,
        const float* __restrict__ w1, const float* __restrict__ b1,
        const float* __restrict__ gamma, const float* __restrict__ beta,
        const float* __restrict__ w3, const float* __restrict__ b3,
        const int* __restrict__ esrc, const int* __restrict__ if_cnt,
        const int* __restrict__ if_bkt, int f, int lane, float lf,
        f2* __restrict__ h2) {
    int srcs[K_FF];
    #pragma unroll
    for (int k = 0; k < K_FF; k++) srcs[k] = esrc[f * K_FF + k];
    // 16 coalesced 1 KB gathers of Hsum rows (bf16, 16 B/lane), all in flight
    uint4 hrow[K_FF];
    #pragma unroll
    for (int k = 0; k < K_FF; k++)
        hrow[k] = *(const uint4*)(Hold + (size_t)srcs[k] * HROW + lane * CCH);

    const f2* b1v = (const f2*)(b1 + (size_t)f * CCH);
    f2 acc2[4];
    #pragma unroll
    for (int q = 0; q < 4; q++) acc2[q] = b1v[q];

    #pragma unroll
    for (int k = 0; k < K_FF; k++) {
        int e = f * K_FF + k;
        const f2* w3v = (const f2*)(w3 + (size_t)e * CCH);   // contiguous rows
        const f2* w1v = (const f2*)(w1 + (size_t)e * CCH);
        f2 d = bfpair(hrow[k].x) * w3v[0];
        d += bfpair(hrow[k].y) * w3v[1];
        d += bfpair(hrow[k].z) * w3v[2];
        d += bfpair(hrow[k].w) * w3v[3];
        float xv = d.x + d.y + lf * b3[e];
        f2 xv2; xv2.x = xv; xv2.y = xv;
        #pragma unroll
        for (int q = 0; q < 4; q++) acc2[q] += xv2 * w1v[q];
    }
    if_accum(acc2, xT, w1, b3, if_cnt, if_bkt, f, lane, lf);
    ln_gelu(acc2, gamma, beta, f, h2);
}

// ---------------- one persistent fused kernel: prep + 4 layers + output ------

__global__ __launch_bounds__(256, 4) void fused(
        unsigned short* __restrict__ HsumA, unsigned short* __restrict__ HsumB,
        const float* __restrict__ x, const float* __restrict__ w1,
        const float* __restrict__ b1, const float* __restrict__ gamma,
        const float* __restrict__ beta, const float* __restrict__ w3,
        const float* __restrict__ b3, const int* __restrict__ esrc,
        const int* __restrict__ edst, int* __restrict__ if_cnt,
        int* __restrict__ if_bkt, float* __restrict__ xT,
        unsigned* __restrict__ bar, float* __restrict__ out) {
    int tid = blockIdx.x * 256 + threadIdx.x;
    int lane = threadIdx.x & 63;
    int gw = tid >> 6;                   // 0..NWAVE-1, wave-uniform

    // ---- phase 0: prep (if buckets + x transpose) ----
    if (tid < E_IF) {
        int e = E_FF + tid;
        int d = edst[e];
        int p = atomicAdd(&if_cnt[d], 1);
        if_bkt[d * IF_CAP + p] = e;
    }
    if (tid < N_IN * BATCH) {            // 128000 < 262144: single pass
        int col = tid >> 6;
        xT[col * BATCH + lane] = x[lane * N_IN + col];
    }
    gsync(bar, 1 * NBLK);

    // ---- layer 1: xe_0 = 0 on ff edges; Hsum_1 = h_1 -> A ----
    for (int f = gw; f < N_FUNC; f += NWAVE) {
        const f2* b1v = (const f2*)(b1 + (size_t)f * CCH);
        f2 acc2[4];
        #pragma unroll
        for (int q = 0; q < 4; q++) acc2[q] = b1v[q];
        if_accum(acc2, xT, w1, b3, if_cnt, if_bkt, f, lane, 0.0f);
        f2 h2[4];
        ln_gelu(acc2, gamma, beta, f, h2);
        uint4 o;
        o.x = bfpack2(h2[0].x, h2[0].y); o.y = bfpack2(h2[1].x, h2[1].y);
        o.z = bfpack2(h2[2].x, h2[2].y); o.w = bfpack2(h2[3].x, h2[3].y);
        *(uint4*)(HsumA + (size_t)f * HROW + lane * CCH) = o;
    }
    gsync(bar, 2 * NBLK);

    // ---- layer 2: A -> B (lf = 1) ----
    for (int f = gw; f < N_FUNC; f += NWAVE) {
        uint4 own = *(const uint4*)(HsumA + (size_t)f * HROW + lane * CCH);
        f2 h2[4];
        compute_h_gather(HsumA, xT, w1, b1, gamma, beta, w3, b3, esrc,
                         if_cnt, if_bkt, f, lane, 1.0f, h2);
        f2 s0 = bfpair(own.x) + h2[0];
        f2 s1 = bfpair(own.y) + h2[1];
        f2 s2 = bfpair(own.z) + h2[2];
        f2 s3 = bfpair(own.w) + h2[3];
        uint4 o;
        o.x = bfpack2(s0.x, s0.y); o.y = bfpack2(s1.x, s1.y);
        o.z = bfpack2(s2.x, s2.y); o.w = bfpack2(s3.x, s3.y);
        *(uint4*)(HsumB + (size_t)f * HROW + lane * CCH) = o;
    }
    gsync(bar, 3 * NBLK);

    // ---- layer 3: B -> A (lf = 2) ----
    for (int f = gw; f < N_FUNC; f += NWAVE) {
        uint4 own = *(const uint4*)(HsumB + (size_t)f * HROW + lane * CCH);
        f2 h2[4];
        compute_h_gather(HsumB, xT, w1, b1, gamma, beta, w3, b3, esrc,
                         if_cnt, if_bkt, f, lane, 2.0f, h2);
        f2 s0 = bfpair(own.x) + h2[0];
        f2 s1 = bfpair(own.y) + h2[1];
        f2 s2 = bfpair(own.z) + h2[2];
        f2 s3 = bfpair(own.w) + h2[3];
        uint4 o;
        o.x = bfpack2(s0.x, s0.y); o.y = bfpack2(s1.x, s1.y);
        o.z = bfpack2(s2.x, s2.y); o.w = bfpack2(s3.x, s3.y);
        *(uint4*)(HsumA + (size_t)f * HROW + lane * CCH) = o;
    }
    gsync(bar, 4 * NBLK);

    // ---- layer 4 + output: only the 2000 fo edges ----
    // out = xe_4[e]/4 = b3[e] + 0.25 * w3[p] . (Hsum_3[s] + h_4[s])
    for (int j = gw; j < N_OUT; j += NWAVE) {
        int e = E_W1 + j;
        int s = __builtin_amdgcn_readfirstlane(esrc[e]);
        uint4 own = *(const uint4*)(HsumA + (size_t)s * HROW + lane * CCH);
        f2 h2[4];
        compute_h_gather(HsumA, xT, w1, b1, gamma, beta, w3, b3, esrc,
                         if_cnt, if_bkt, s, lane, 3.0f, h2);
        f2 Hf0 = bfpair(own.x) + h2[0];
        f2 Hf1 = bfpair(own.y) + h2[1];
        f2 Hf2 = bfpair(own.z) + h2[2];
        f2 Hf3 = bfpair(own.w) + h2[3];
        int p = e - E_IF;
        const f2* w3v = (const f2*)(w3 + (size_t)p * CCH);
        f2 a = Hf0 * w3v[0];
        a += Hf1 * w3v[1];
        a += Hf2 * w3v[2];
        a += Hf3 * w3v[3];
        out[lane * N_OUT + j] = b3[e] + 0.25f * (a.x + a.y);
    }
}

// ---------------- launch ----------------

extern "C" void kernel_launch(void* const* d_in, const int* in_sizes, int n_in,
                              void* d_out, int out_size, void* d_ws, size_t ws_size,
                              hipStream_t stream) {
    const float* x      = (const float*)d_in[0];
    const float* w1_val = (const float*)d_in[1];
    const float* b1     = (const float*)d_in[2];
    const float* w3_val = (const float*)d_in[3];
    const float* b3     = (const float*)d_in[4];
    const float* gamma  = (const float*)d_in[5];
    const float* beta   = (const float*)d_in[6];
    const int* edge_src = (const int*)d_in[7];
    const int* edge_dst = (const int*)d_in[8];
    float* out = (float*)d_out;

    char* base = (char*)d_ws;
    size_t off = 0;
    auto alloc = [&](size_t bytes) -> void* {
        void* p = base + off;
        off += (bytes + 255) & ~(size_t)255;
        return p;
    };
    unsigned short* HsumA = (unsigned short*)alloc((size_t)N_FUNC * HROW * 2);  // 10.24 MB bf16
    unsigned short* HsumB = (unsigned short*)alloc((size_t)N_FUNC * HROW * 2);
    float* xT    = (float*)alloc((size_t)N_IN * BATCH * 4);
    int*   ints  = (int*)alloc((size_t)(N_FUNC + 64) * 4);   // if_cnt | bar
    int* if_cnt  = ints;
    unsigned* bar = (unsigned*)(ints + N_FUNC);
    int* if_bkt  = (int*)alloc((size_t)N_FUNC * IF_CAP * 4);
    (void)ws_size; (void)in_sizes; (void)n_in; (void)out_size;

    hipMemsetAsync(ints, 0, (size_t)(N_FUNC + 64) * 4, stream);   // capture-legal

    fused<<<NBLK, 256, 0, stream>>>(
        HsumA, HsumB, x, w1_val, b1, gamma, beta, w3_val, b3,
        edge_src, edge_dst, if_cnt, if_bkt, xT, bar, out);
}

// Round 4
// 398.010 us; speedup vs baseline: 2.1321x; 2.1321x over previous
//
#include <hip/hip_runtime.h>

#define N_FUNC 10000
#define N_IN   2000
#define N_OUT  2000
#define CCH    8
#define K_FF   16
#define E_FF    160000   // ff edges: dst[e] = e/16 (structural), src random func
#define E_W1    168000   // ff+if edges (dst < N_FUNC)
#define E_IF    8000
#define BATCH   64
#define EPS_LN  1e-5f
#define IF_CAP  16        // max if-in-degree of a func node (mean 0.8)
#define HROW    (BATCH * CCH)   // Hsum row: 512 ushorts (bf16) = 1 KB per node
#define NSHARD  8         // batch shards of 8 -> 128 B/node/shard, 1.28 MB/shard (fits XCD L2)

typedef float f2 __attribute__((ext_vector_type(2)));   // -> v_pk_fma_f32

// ---- bf16 helpers (fp32 math everywhere; RNE on store) ----
__device__ __forceinline__ f2 bfpair(unsigned int u) {   // packed pair -> 2 floats
    f2 r;
    r.x = __builtin_bit_cast(float, u << 16);
    r.y = __builtin_bit_cast(float, u & 0xffff0000u);
    return r;
}
__device__ __forceinline__ unsigned int bfpack2(float f0, float f1) {
    unsigned int x0 = __builtin_bit_cast(unsigned int, f0);
    unsigned int x1 = __builtin_bit_cast(unsigned int, f1);
    unsigned int r0 = (x0 + 0x7fffu + ((x0 >> 16) & 1u)) >> 16;
    unsigned int r1 = (x1 + 0x7fffu + ((x1 >> 16) & 1u)) & 0xffff0000u;
    return r0 | r1;
}
__device__ __forceinline__ unsigned short bf1(float f) {   // single bf16 RNE
    unsigned int x = __builtin_bit_cast(unsigned int, f);
    return (unsigned short)((x + 0x7fffu + ((x >> 16) & 1u)) >> 16);
}
__device__ __forceinline__ float unbf1(unsigned short u) {
    return __builtin_bit_cast(float, (unsigned int)u << 16);
}

// fast GELU (validated: absmax unchanged vs exact erf)
__device__ __forceinline__ float fast_gelu(float x) {
    float x2 = x * x;
    float u  = x * __builtin_fmaf(0.044715f, x2, 1.0f);
    float e  = exp2f(-2.3022080f * u);     // sigmoid(1.5957691*u)
    return x * (1.0f / (1.0f + e));
}

// sum over the 8 ch-lanes of each 8-lane group (lane = b*8 + c)
__device__ __forceinline__ float reduce8(float t) {
    t += __shfl_xor(t, 1);
    t += __shfl_xor(t, 2);
    t += __shfl_xor(t, 4);
    return t;
}

// ---------------- prep: if-edge buckets + x transpose (round-0 form) ---------

__global__ void fill_prep(const int* __restrict__ dst, const float* __restrict__ x,
                          int* __restrict__ if_cnt, int* __restrict__ if_bkt,
                          float* __restrict__ xT) {
    int i = blockIdx.x * blockDim.x + threadIdx.x;
    if (i < E_IF) {
        int e = E_FF + i;
        int d = dst[e];
        int pos = atomicAdd(&if_cnt[d], 1);
        if_bkt[d * IF_CAP + pos] = e;
    }
    if (i < N_IN * BATCH) {
        int col = i >> 6, lane = i & 63;
        xT[col * BATCH + lane] = x[lane * N_IN + col];
    }
}

// ---------------- round-0 f2 helpers (used by block_first only) --------------

__device__ __forceinline__ void if_accum(
        f2* __restrict__ acc2, const float* __restrict__ xT,
        const float* __restrict__ w1, const float* __restrict__ b3,
        const int* __restrict__ if_cnt, const int* __restrict__ if_bkt,
        int f, int lane, float lf) {
    int icnt = if_cnt[f];
    for (int j = 0; j < icnt; j++) {
        int e = if_bkt[f * IF_CAP + j];
        int ii = (e - E_FF) >> 2;
        float xv = xT[ii * BATCH + lane] + lf * b3[e];
        f2 xv2; xv2.x = xv; xv2.y = xv;
        const f2* w1v = (const f2*)(w1 + (size_t)e * CCH);
        #pragma unroll
        for (int q = 0; q < 4; q++) acc2[q] += xv2 * w1v[q];
    }
}

__device__ __forceinline__ void ln_gelu(
        const f2* __restrict__ acc2, const float* __restrict__ gamma,
        const float* __restrict__ beta, int f, f2* __restrict__ h2) {
    float mu = 0.f;
    #pragma unroll
    for (int q = 0; q < 4; q++) mu += acc2[q].x + acc2[q].y;
    mu *= 0.125f;
    float var = 0.f;
    #pragma unroll
    for (int q = 0; q < 4; q++) {
        float dx = acc2[q].x - mu, dy = acc2[q].y - mu;
        var += dx * dx + dy * dy;
    }
    var *= 0.125f;
    float rs = rsqrtf(var + EPS_LN);
    const f2* gv = (const f2*)(gamma + (size_t)f * CCH);
    const f2* bv = (const f2*)(beta + (size_t)f * CCH);
    f2 mu2; mu2.x = mu; mu2.y = mu;
    f2 rs2; rs2.x = rs; rs2.y = rs;
    #pragma unroll
    for (int q = 0; q < 4; q++) {
        f2 g = (acc2[q] - mu2) * rs2 * gv[q] + bv[q];
        h2[q].x = fast_gelu(g.x);
        h2[q].y = fast_gelu(g.y);
    }
}

// ---------------- shard-form h: wave = (node f, batch-shard), lane = b*8+c ---
// gathers touch only slice `shard` of Hold: 128 B contiguous per src row.

__device__ __forceinline__ float compute_h_shard(
        const unsigned short* __restrict__ Hold, const float* __restrict__ xT,
        const float* __restrict__ w1, const float* __restrict__ b1,
        const float* __restrict__ gamma, const float* __restrict__ beta,
        const float* __restrict__ w3, const float* __restrict__ b3,
        const int* __restrict__ esrc, const int* __restrict__ if_cnt,
        const int* __restrict__ if_bkt, int f, int shard, int lane, float lf) {
    int c  = lane & 7;
    int bg = shard * 8 + (lane >> 3);     // global batch index
    int e0 = f * K_FF;

    int srcs[K_FF];                        // wave-uniform -> s_loads
    #pragma unroll
    for (int k = 0; k < K_FF; k++) srcs[k] = esrc[e0 + k];

    // 16 independent 128-B slice gathers (2 B/lane), all in flight
    float hk[K_FF];
    #pragma unroll
    for (int k = 0; k < K_FF; k++)
        hk[k] = unbf1(Hold[(size_t)srcs[k] * HROW + shard * 64 + lane]);

    float acc = b1[(size_t)f * CCH + c];
    #pragma unroll
    for (int k = 0; k < K_FF; k++) {
        int e = e0 + k;
        float t  = hk[k] * w3[(size_t)e * CCH + c];
        float xv = reduce8(t) + lf * b3[e];          // dot8 over ch-lanes
        acc = __builtin_fmaf(xv, w1[(size_t)e * CCH + c], acc);
    }
    int icnt = if_cnt[f];
    for (int j = 0; j < icnt; j++) {
        int e = if_bkt[f * IF_CAP + j];
        int ii = (e - E_FF) >> 2;
        float xv = xT[ii * BATCH + bg] + lf * b3[e];
        acc = __builtin_fmaf(xv, w1[(size_t)e * CCH + c], acc);
    }
    // group-LN over the 8 ch-lanes + gelu
    float mu = reduce8(acc) * 0.125f;
    float d  = acc - mu;
    float var = reduce8(d * d) * 0.125f;
    float rs = rsqrtf(var + EPS_LN);
    float g = __builtin_fmaf(d * rs, gamma[(size_t)f * CCH + c],
                             beta[(size_t)f * CCH + c]);
    return fast_gelu(g);
}

// ---------------- block 1: xe_0 = 0 on ff edges; Hsum_1 = h_1 (round-0) ------

__global__ __launch_bounds__(256, 4) void block_first(
        unsigned short* __restrict__ Hnew, const float* __restrict__ xT,
        const float* __restrict__ w1, const float* __restrict__ b1,
        const float* __restrict__ gamma, const float* __restrict__ beta,
        const float* __restrict__ b3, const int* __restrict__ if_cnt,
        const int* __restrict__ if_bkt) {
    int wid = (blockIdx.x * blockDim.x + threadIdx.x) >> 6;
    int lane = threadIdx.x & 63;
    int f = __builtin_amdgcn_readfirstlane(wid);
    if (f >= N_FUNC) return;
    const f2* b1v = (const f2*)(b1 + (size_t)f * CCH);
    f2 acc2[4];
    #pragma unroll
    for (int q = 0; q < 4; q++) acc2[q] = b1v[q];
    if_accum(acc2, xT, w1, b3, if_cnt, if_bkt, f, lane, 0.0f);
    f2 h2[4];
    ln_gelu(acc2, gamma, beta, f, h2);
    uint4 o;
    o.x = bfpack2(h2[0].x, h2[0].y); o.y = bfpack2(h2[1].x, h2[1].y);
    o.z = bfpack2(h2[2].x, h2[2].y); o.w = bfpack2(h2[3].x, h2[3].y);
    *(uint4*)(Hnew + (size_t)f * HROW + lane * CCH) = o;
}

// ---------------- blocks 2,3 (sharded): shard = blockIdx & 7 -> same XCD -----

__global__ __launch_bounds__(256, 8) void block_mid_s(
        const unsigned short* __restrict__ Hold, unsigned short* __restrict__ Hnew,
        const float* __restrict__ xT, const float* __restrict__ w1,
        const float* __restrict__ b1, const float* __restrict__ gamma,
        const float* __restrict__ beta, const float* __restrict__ w3,
        const float* __restrict__ b3, const int* __restrict__ esrc,
        const int* __restrict__ if_cnt, const int* __restrict__ if_bkt, float lf) {
    int shard = blockIdx.x & 7;                       // blockIdx%8 ~ XCD (round-robin)
    int lane  = threadIdx.x & 63;
    int f = __builtin_amdgcn_readfirstlane((blockIdx.x >> 3) * 4 + (threadIdx.x >> 6));
    // 8 * (N_FUNC/4) blocks: f < N_FUNC always
    size_t oidx = (size_t)f * HROW + shard * 64 + lane;
    float own = unbf1(Hold[oidx]);                    // own slice, issued early
    float h = compute_h_shard(Hold, xT, w1, b1, gamma, beta, w3, b3,
                              esrc, if_cnt, if_bkt, f, shard, lane, lf);
    Hnew[oidx] = bf1(own + h);                        // 128-B contiguous store
}

// ---------------- block 4 + output (sharded): only the 2000 fo edges ---------
// out = xe_4[e]/4 = b3[e] + 0.25 * w3[p] . (Hsum_3[s] + h_4[s])

__global__ __launch_bounds__(256, 8) void block_out_s(
        const unsigned short* __restrict__ Hold, const float* __restrict__ xT,
        const float* __restrict__ w1, const float* __restrict__ b1,
        const float* __restrict__ gamma, const float* __restrict__ beta,
        const float* __restrict__ w3, const float* __restrict__ b3,
        const int* __restrict__ esrc, const int* __restrict__ if_cnt,
        const int* __restrict__ if_bkt, float* __restrict__ out) {
    int shard = blockIdx.x & 7;
    int lane  = threadIdx.x & 63;
    int j = __builtin_amdgcn_readfirstlane((blockIdx.x >> 3) * 4 + (threadIdx.x >> 6));
    // 8 * (N_OUT/4) blocks: j < N_OUT always
    int e = E_W1 + j;
    int s = __builtin_amdgcn_readfirstlane(esrc[e]);

    float own = unbf1(Hold[(size_t)s * HROW + shard * 64 + lane]);
    float h = compute_h_shard(Hold, xT, w1, b1, gamma, beta, w3, b3,
                              esrc, if_cnt, if_bkt, s, shard, lane, 3.0f);
    float Hf = own + h;

    int p = e - E_IF;
    float a = reduce8(Hf * w3[(size_t)p * CCH + (lane & 7)]);
    if ((lane & 7) == 0)
        out[(size_t)(shard * 8 + (lane >> 3)) * N_OUT + j] = b3[e] + 0.25f * a;
}

// ---------------- launch ----------------

extern "C" void kernel_launch(void* const* d_in, const int* in_sizes, int n_in,
                              void* d_out, int out_size, void* d_ws, size_t ws_size,
                              hipStream_t stream) {
    const float* x      = (const float*)d_in[0];
    const float* w1_val = (const float*)d_in[1];
    const float* b1     = (const float*)d_in[2];
    const float* w3_val = (const float*)d_in[3];
    const float* b3     = (const float*)d_in[4];
    const float* gamma  = (const float*)d_in[5];
    const float* beta   = (const float*)d_in[6];
    const int* edge_src = (const int*)d_in[7];
    const int* edge_dst = (const int*)d_in[8];
    float* out = (float*)d_out;

    char* base = (char*)d_ws;
    size_t off = 0;
    auto alloc = [&](size_t bytes) -> void* {
        void* p = base + off;
        off += (bytes + 255) & ~(size_t)255;
        return p;
    };
    unsigned short* HsumA = (unsigned short*)alloc((size_t)N_FUNC * HROW * 2);  // 10.24 MB bf16
    unsigned short* HsumB = (unsigned short*)alloc((size_t)N_FUNC * HROW * 2);
    float* xT    = (float*)alloc((size_t)N_IN * BATCH * 4);
    int* if_cnt  = (int*)alloc(N_FUNC * 4);
    int* if_bkt  = (int*)alloc((size_t)N_FUNC * IF_CAP * 4);
    (void)ws_size; (void)in_sizes; (void)n_in; (void)out_size;

    hipMemsetAsync(if_cnt, 0, N_FUNC * 4, stream);   // capture-legal

    fill_prep<<<(N_IN * BATCH + 255) / 256, 256, 0, stream>>>(
        edge_dst, x, if_cnt, if_bkt, xT);

    // block 1: Hsum_1 = h_1 -> A  (full-row form)
    block_first<<<(N_FUNC * BATCH) / 256, 256, 0, stream>>>(
        HsumA, xT, w1_val, b1, gamma, beta, b3, if_cnt, if_bkt);

    // block 2: A -> B (lf = 1), sharded: 8 x 2500 blocks
    block_mid_s<<<NSHARD * (N_FUNC / 4), 256, 0, stream>>>(
        HsumA, HsumB, xT, w1_val, b1, gamma, beta, w3_val, b3,
        edge_src, if_cnt, if_bkt, 1.0f);

    // block 3: B -> A (lf = 2)
    block_mid_s<<<NSHARD * (N_FUNC / 4), 256, 0, stream>>>(
        HsumB, HsumA, xT, w1_val, b1, gamma, beta, w3_val, b3,
        edge_src, if_cnt, if_bkt, 2.0f);

    // block 4 + output: reads Hsum_3 = A (lf = 3), sharded: 8 x 500 blocks
    block_out_s<<<NSHARD * (N_OUT / 4), 256, 0, stream>>>(
        HsumA, xT, w1_val, b1, gamma, beta, w3_val, b3,
        edge_src, if_cnt, if_bkt, out);
}

// Round 5
// 199.874 us; speedup vs baseline: 4.2458x; 1.9913x over previous
//
#include <hip/hip_runtime.h>

#define N_FUNC 10000
#define N_IN   2000
#define N_OUT  2000
#define CCH    8
#define K_FF   16
#define E_FF    160000   // ff edges: dst[e] = e/16 (structural), src random func
#define E_W1    168000   // ff+if edges (dst < N_FUNC)
#define E_IF    8000
#define BATCH   64
#define EPS_LN  1e-5f
#define IF_CAP  16        // max if-in-degree of a func node (mean 0.8)
#define OUT_CAP 64        // max ff-out-degree (Poisson mean 16; P(>=64) ~ 1e-20)
#define HROW    (BATCH * CCH)   // Hsum row: 512 ushorts (bf16) = 1 KB per node

typedef float f2 __attribute__((ext_vector_type(2)));   // -> v_pk_fma_f32

// ---- bf16 helpers (fp32 math everywhere; RNE on store) ----
__device__ __forceinline__ f2 bfpair(unsigned int u) {   // packed pair -> 2 floats
    f2 r;
    r.x = __builtin_bit_cast(float, u << 16);
    r.y = __builtin_bit_cast(float, u & 0xffff0000u);
    return r;
}
__device__ __forceinline__ unsigned int bfpack2(float f0, float f1) {
    unsigned int x0 = __builtin_bit_cast(unsigned int, f0);
    unsigned int x1 = __builtin_bit_cast(unsigned int, f1);
    unsigned int r0 = (x0 + 0x7fffu + ((x0 >> 16) & 1u)) >> 16;
    unsigned int r1 = (x1 + 0x7fffu + ((x1 >> 16) & 1u)) & 0xffff0000u;
    return r0 | r1;
}
__device__ __forceinline__ unsigned short bf1(float f) {   // single bf16 RNE
    unsigned int x = __builtin_bit_cast(unsigned int, f);
    return (unsigned short)((x + 0x7fffu + ((x >> 16) & 1u)) >> 16);
}
__device__ __forceinline__ float unbf1(unsigned short u) {
    return __builtin_bit_cast(float, (unsigned int)u << 16);
}

// fast GELU (validated: absmax unchanged vs exact erf)
__device__ __forceinline__ float fast_gelu(float x) {
    float x2 = x * x;
    float u  = x * __builtin_fmaf(0.044715f, x2, 1.0f);
    float e  = exp2f(-2.3022080f * u);     // sigmoid(1.5957691*u)
    return x * (1.0f / (1.0f + e));
}

// ---------------- prep: if buckets + src-CSR + slot-ordered w3/b3 + needed + xT
// (if_cnt/out_cnt/needed zeroed by one hipMemsetAsync on the stream)

__global__ void fill_prep(const int* __restrict__ src, const int* __restrict__ dst,
                          const float* __restrict__ x, const float* __restrict__ w3,
                          const float* __restrict__ b3,
                          int* __restrict__ if_cnt, int* __restrict__ if_bkt,
                          int* __restrict__ out_cnt, int* __restrict__ out_bkt,
                          float* __restrict__ w3s, float* __restrict__ b3s,
                          int* __restrict__ needed, float* __restrict__ xT) {
    int i = blockIdx.x * blockDim.x + threadIdx.x;
    if (i < E_FF) {                       // CSR of ff edges grouped by src
        int s = src[i];
        int j = atomicAdd(&out_cnt[s], 1);
        int slot = s * OUT_CAP + j;
        out_bkt[slot] = i;                // scattered (prep-only)
        b3s[slot] = b3[i];
        const float* wsrc = w3 + (size_t)i * CCH;      // sequential read
        float* wdst = w3s + (size_t)slot * CCH;        // scattered 32-B write
        #pragma unroll
        for (int q = 0; q < CCH; q++) wdst[q] = wsrc[q];
    }
    if (i < E_IF) {
        int e = E_FF + i;
        int d = dst[e];
        int p = atomicAdd(&if_cnt[d], 1);
        if_bkt[d * IF_CAP + p] = e;
    }
    if (i < N_IN * BATCH) {
        int col = i >> 6, lane = i & 63;
        xT[col * BATCH + lane] = x[lane * N_IN + col];
    }
    if (i < N_OUT) {                      // nodes whose h_4 feeds an fo edge
        needed[src[E_W1 + i]] = 1;
    }
}

// ---------------- shared pieces (float2-packed) ----------------

// if-edge contributions: virtual xe value = xT[i] + lf*b3[e]
__device__ __forceinline__ void if_accum(
        f2* __restrict__ acc2, const float* __restrict__ xT,
        const float* __restrict__ w1, const float* __restrict__ b3,
        const int* __restrict__ if_cnt, const int* __restrict__ if_bkt,
        int f, int lane, float lf) {
    int icnt = if_cnt[f];
    for (int j = 0; j < icnt; j++) {
        int e = if_bkt[f * IF_CAP + j];
        int ii = (e - E_FF) >> 2;
        float xv = xT[ii * BATCH + lane] + lf * b3[e];
        f2 xv2; xv2.x = xv; xv2.y = xv;
        const f2* w1v = (const f2*)(w1 + (size_t)e * CCH);
        #pragma unroll
        for (int q = 0; q < 4; q++) acc2[q] += xv2 * w1v[q];
    }
}

__device__ __forceinline__ void ln_gelu(
        const f2* __restrict__ acc2, const float* __restrict__ gamma,
        const float* __restrict__ beta, int f, f2* __restrict__ h2) {
    float mu = 0.f;
    #pragma unroll
    for (int q = 0; q < 4; q++) mu += acc2[q].x + acc2[q].y;
    mu *= 0.125f;
    float var = 0.f;
    #pragma unroll
    for (int q = 0; q < 4; q++) {
        float dx = acc2[q].x - mu, dy = acc2[q].y - mu;
        var += dx * dx + dy * dy;
    }
    var *= 0.125f;
    float rs = rsqrtf(var + EPS_LN);
    const f2* gv = (const f2*)(gamma + (size_t)f * CCH);
    const f2* bv = (const f2*)(beta + (size_t)f * CCH);
    f2 mu2; mu2.x = mu; mu2.y = mu;
    f2 rs2; rs2.x = rs; rs2.y = rs;
    #pragma unroll
    for (int q = 0; q < 4; q++) {
        f2 g = (acc2[q] - mu2) * rs2 * gv[q] + bv[q];
        h2[q].x = fast_gelu(g.x);
        h2[q].y = fast_gelu(g.y);
    }
}

// h for node f from EDGE-ORDERED bf16 v: one contiguous 2-KB sequential read.
__device__ __forceinline__ void compute_h_from_v(
        const unsigned short* __restrict__ vin, const float* __restrict__ xT,
        const float* __restrict__ w1, const float* __restrict__ b1,
        const float* __restrict__ gamma, const float* __restrict__ beta,
        const float* __restrict__ b3, const int* __restrict__ if_cnt,
        const int* __restrict__ if_bkt, int f, int lane, float lf,
        f2* __restrict__ h2) {
    const unsigned short* vbase = vin + (size_t)f * K_FF * BATCH + lane;
    float xv[K_FF];
    #pragma unroll
    for (int k = 0; k < K_FF; k++) xv[k] = unbf1(vbase[(size_t)k * BATCH]);

    const f2* b1v = (const f2*)(b1 + (size_t)f * CCH);
    f2 acc2[4];
    #pragma unroll
    for (int q = 0; q < 4; q++) acc2[q] = b1v[q];

    #pragma unroll
    for (int k = 0; k < K_FF; k++) {
        const f2* w1v = (const f2*)(w1 + (size_t)(f * K_FF + k) * CCH);  // sequential
        f2 xv2; xv2.x = xv[k]; xv2.y = xv[k];
        #pragma unroll
        for (int q = 0; q < 4; q++) acc2[q] += xv2 * w1v[q];
    }
    if_accum(acc2, xT, w1, b3, if_cnt, if_bkt, f, lane, lf);
    ln_gelu(acc2, gamma, beta, f, h2);
}

// producer tail: wave holds NEW fp32 Hsum row of node f in Hf[4]; emit
// next-layer edge values. Loads (w3s/b3s/out_bkt) are SEQUENTIAL (slot order);
// only the store address is scattered (fire-and-forget 128-B stores).
__device__ __forceinline__ void emit_v(
        const f2* __restrict__ Hf, const float* __restrict__ w3s,
        const float* __restrict__ b3s, const int* __restrict__ out_cnt,
        const int* __restrict__ out_bkt, const int* __restrict__ needed,
        unsigned short* __restrict__ vout, int f, int lane, float lfn, int prune) {
    int cnt = __builtin_amdgcn_readfirstlane(out_cnt[f]);
    int base = f * OUT_CAP;
    for (int j = 0; j < cnt; j++) {
        int e = __builtin_amdgcn_readfirstlane(out_bkt[base + j]);   // sequential
        if (prune && !needed[e >> 4]) continue;   // e>>4 == dst (structural)
        const f2* wv = (const f2*)(w3s + (size_t)(base + j) * CCH);  // sequential
        f2 d = Hf[0] * wv[0];
        d += Hf[1] * wv[1];
        d += Hf[2] * wv[2];
        d += Hf[3] * wv[3];
        vout[(size_t)e * BATCH + lane] =
            bf1(__builtin_fmaf(lfn, b3s[base + j], d.x + d.y));
    }
}

// ---------------- block 1: xe_0 = 0 on ff edges; Hsum_1 = h_1; emit v_2 ------

__global__ __launch_bounds__(256, 4) void block_first(
        unsigned short* __restrict__ Hnew, unsigned short* __restrict__ vout,
        const float* __restrict__ xT, const float* __restrict__ w1,
        const float* __restrict__ b1, const float* __restrict__ gamma,
        const float* __restrict__ beta, const float* __restrict__ w3s,
        const float* __restrict__ b3, const float* __restrict__ b3s,
        const int* __restrict__ if_cnt, const int* __restrict__ if_bkt,
        const int* __restrict__ out_cnt, const int* __restrict__ out_bkt) {
    int wid = (blockIdx.x * blockDim.x + threadIdx.x) >> 6;
    int lane = threadIdx.x & 63;
    int f = __builtin_amdgcn_readfirstlane(wid);
    if (f >= N_FUNC) return;
    const f2* b1v = (const f2*)(b1 + (size_t)f * CCH);
    f2 acc2[4];
    #pragma unroll
    for (int q = 0; q < 4; q++) acc2[q] = b1v[q];
    if_accum(acc2, xT, w1, b3, if_cnt, if_bkt, f, lane, 0.0f);
    f2 h2[4];
    ln_gelu(acc2, gamma, beta, f, h2);
    uint4 o;
    o.x = bfpack2(h2[0].x, h2[0].y); o.y = bfpack2(h2[1].x, h2[1].y);
    o.z = bfpack2(h2[2].x, h2[2].y); o.w = bfpack2(h2[3].x, h2[3].y);
    *(uint4*)(Hnew + (size_t)f * HROW + lane * CCH) = o;
    emit_v(h2, w3s, b3s, out_cnt, out_bkt, (const int*)0, vout, f, lane, 1.0f, 0);
}

// ---------------- blocks 2,3: v (seq) -> h -> Hsum RMW -> emit next v --------

__global__ __launch_bounds__(256, 4) void block_mid(
        const unsigned short* __restrict__ Hold, unsigned short* __restrict__ Hnew,
        const unsigned short* __restrict__ vin, unsigned short* __restrict__ vout,
        const float* __restrict__ xT, const float* __restrict__ w1,
        const float* __restrict__ b1, const float* __restrict__ gamma,
        const float* __restrict__ beta, const float* __restrict__ w3s,
        const float* __restrict__ b3, const float* __restrict__ b3s,
        const int* __restrict__ if_cnt, const int* __restrict__ if_bkt,
        const int* __restrict__ out_cnt, const int* __restrict__ out_bkt,
        const int* __restrict__ needed, float lf, int prune) {
    int wid = (blockIdx.x * blockDim.x + threadIdx.x) >> 6;
    int lane = threadIdx.x & 63;
    int f = __builtin_amdgcn_readfirstlane(wid);
    if (f >= N_FUNC) return;
    // own row issued early to overlap with sequential v reads
    uint4 own = *(const uint4*)(Hold + (size_t)f * HROW + lane * CCH);
    f2 h2[4];
    compute_h_from_v(vin, xT, w1, b1, gamma, beta, b3, if_cnt, if_bkt,
                     f, lane, lf, h2);
    f2 Hf[4];
    Hf[0] = bfpair(own.x) + h2[0];
    Hf[1] = bfpair(own.y) + h2[1];
    Hf[2] = bfpair(own.z) + h2[2];
    Hf[3] = bfpair(own.w) + h2[3];
    uint4 o;
    o.x = bfpack2(Hf[0].x, Hf[0].y); o.y = bfpack2(Hf[1].x, Hf[1].y);
    o.z = bfpack2(Hf[2].x, Hf[2].y); o.w = bfpack2(Hf[3].x, Hf[3].y);
    *(uint4*)(Hnew + (size_t)f * HROW + lane * CCH) = o;
    emit_v(Hf, w3s, b3s, out_cnt, out_bkt, needed, vout, f, lane, lf + 1.0f, prune);
}

// ---------------- block 4 + output: only the 2000 fo edges -------------------
// out = xe_4[e]/4 = b3[e] + 0.25 * w3[p] . (Hsum_3[s] + h_4[s])

__global__ __launch_bounds__(256, 4) void block_out(
        const unsigned short* __restrict__ Hold, const unsigned short* __restrict__ vin,
        const float* __restrict__ xT, const float* __restrict__ w1,
        const float* __restrict__ b1, const float* __restrict__ gamma,
        const float* __restrict__ beta, const float* __restrict__ w3,
        const float* __restrict__ b3, const int* __restrict__ esrc,
        const int* __restrict__ if_cnt, const int* __restrict__ if_bkt,
        float* __restrict__ out) {
    int wid = (blockIdx.x * blockDim.x + threadIdx.x) >> 6;   // fo index
    int lane = threadIdx.x & 63;
    int j = __builtin_amdgcn_readfirstlane(wid);
    if (j >= N_OUT) return;
    int e = E_W1 + j;
    int s = __builtin_amdgcn_readfirstlane(esrc[e]);

    uint4 own = *(const uint4*)(Hold + (size_t)s * HROW + lane * CCH);
    f2 h2[4];
    compute_h_from_v(vin, xT, w1, b1, gamma, beta, b3, if_cnt, if_bkt,
                     s, lane, 3.0f, h2);
    f2 Hf0 = bfpair(own.x) + h2[0];
    f2 Hf1 = bfpair(own.y) + h2[1];
    f2 Hf2 = bfpair(own.z) + h2[2];
    f2 Hf3 = bfpair(own.w) + h2[3];

    int p = e - E_IF;
    const f2* w3v = (const f2*)(w3 + (size_t)p * CCH);
    f2 a = Hf0 * w3v[0];
    a += Hf1 * w3v[1];
    a += Hf2 * w3v[2];
    a += Hf3 * w3v[3];
    out[lane * N_OUT + j] = b3[e] + 0.25f * (a.x + a.y);
}

// ---------------- launch ----------------

extern "C" void kernel_launch(void* const* d_in, const int* in_sizes, int n_in,
                              void* d_out, int out_size, void* d_ws, size_t ws_size,
                              hipStream_t stream) {
    const float* x      = (const float*)d_in[0];
    const float* w1_val = (const float*)d_in[1];
    const float* b1     = (const float*)d_in[2];
    const float* w3_val = (const float*)d_in[3];
    const float* b3     = (const float*)d_in[4];
    const float* gamma  = (const float*)d_in[5];
    const float* beta   = (const float*)d_in[6];
    const int* edge_src = (const int*)d_in[7];
    const int* edge_dst = (const int*)d_in[8];
    float* out = (float*)d_out;

    char* base = (char*)d_ws;
    size_t off = 0;
    auto alloc = [&](size_t bytes) -> void* {
        void* p = base + off;
        off += (bytes + 255) & ~(size_t)255;
        return p;
    };
    unsigned short* HsumA = (unsigned short*)alloc((size_t)N_FUNC * HROW * 2);  // 10.24 MB bf16
    unsigned short* HsumB = (unsigned short*)alloc((size_t)N_FUNC * HROW * 2);
    float* xT    = (float*)alloc((size_t)N_IN * BATCH * 4);
    int*   cnts  = (int*)alloc((size_t)3 * N_FUNC * 4);   // if_cnt | out_cnt | needed
    int* if_cnt  = cnts;
    int* out_cnt = cnts + N_FUNC;
    int* needed  = cnts + 2 * N_FUNC;
    int* if_bkt  = (int*)alloc((size_t)N_FUNC * IF_CAP * 4);
    int* out_bkt = (int*)alloc((size_t)N_FUNC * OUT_CAP * 4);          // 2.56 MB
    float* w3s   = (float*)alloc((size_t)N_FUNC * OUT_CAP * CCH * 4);  // 20.5 MB slot-ordered
    float* b3s   = (float*)alloc((size_t)N_FUNC * OUT_CAP * 4);        // 2.56 MB
    // bf16 edge values, EDGE-ordered, double-buffered (20.48 MB each)
    unsigned short* vA = (unsigned short*)alloc((size_t)E_FF * BATCH * 2);
    unsigned short* vB = (unsigned short*)alloc((size_t)E_FF * BATCH * 2);
    (void)ws_size; (void)in_sizes; (void)n_in; (void)out_size;

    hipMemsetAsync(cnts, 0, (size_t)3 * N_FUNC * 4, stream);   // capture-legal
    fill_prep<<<(E_FF + 255) / 256, 256, 0, stream>>>(
        edge_src, edge_dst, x, w3_val, b3, if_cnt, if_bkt,
        out_cnt, out_bkt, w3s, b3s, needed, xT);

    // block 1: Hsum_1 = h_1 -> A ; emit v_2 -> vA
    block_first<<<(N_FUNC * BATCH) / 256, 256, 0, stream>>>(
        HsumA, vA, xT, w1_val, b1, gamma, beta, w3s, b3, b3s,
        if_cnt, if_bkt, out_cnt, out_bkt);

    // block 2: A -> B (lf = 1); consume vA, emit v_3 -> vB
    block_mid<<<(N_FUNC * BATCH) / 256, 256, 0, stream>>>(
        HsumA, HsumB, vA, vB, xT, w1_val, b1, gamma, beta, w3s, b3, b3s,
        if_cnt, if_bkt, out_cnt, out_bkt, needed, 1.0f, 0);

    // block 3: B -> A (lf = 2); consume vB, emit pruned v_4 -> vA
    block_mid<<<(N_FUNC * BATCH) / 256, 256, 0, stream>>>(
        HsumB, HsumA, vB, vA, xT, w1_val, b1, gamma, beta, w3s, b3, b3s,
        if_cnt, if_bkt, out_cnt, out_bkt, needed, 2.0f, 1);

    // block 4 + output: reads Hsum_3 = A and pruned v_4 = vA (lf = 3)
    block_out<<<(N_OUT * BATCH) / 256, 256, 0, stream>>>(
        HsumA, vA, xT, w1_val, b1, gamma, beta, w3_val, b3,
        edge_src, if_cnt, if_bkt, out);
}